// Round 2
// baseline (1651.982 us; speedup 1.0000x reference)
//
#include <hip/hip_runtime.h>

#define HOUT 15
#define WOUT 15
// input  (32, 32, 32, 32, 16)  fp32
// ncv    (32, 32, 15, 15, 16)  fp32
// w      (3, 3, 32, 4, 4, 32)  fp32  -> slice per n: 9 chunks of 512 floats
// out    (32, 32, 15, 15, 16)  fp32

#define ASG __attribute__((address_space(1)))
#define ASL __attribute__((address_space(3)))

// One 32-lane group per output position (b,h,w); lane = m. 8 groups / block.
// Block loops n=0..31; w[:,:,n,:,:,:] staged in LDS (double-buffered, async).
__global__ __launch_bounds__(256, 4) void caps_fused(
    const float* __restrict__ input,
    const float* __restrict__ ncv,
    const float* __restrict__ wt,
    const float* __restrict__ gamma,
    const float* __restrict__ beta,
    float* __restrict__ out)
{
    __shared__ float lw[2][4608];   // 2 x 18KB

    const int tid   = threadIdx.x;
    const int grp   = tid >> 5;     // 0..7
    const int lane  = tid & 31;     // m
    const int wv    = tid >> 6;     // wave 0..3
    const int wlane = tid & 63;

    const int pos = blockIdx.x * 8 + grp;
    const int b   = pos / (HOUT * WOUT);
    const int hw  = pos % (HOUT * WOUT);
    const int h   = hw / WOUT;
    const int wo  = hw % WOUT;

    // ---- async stage of w slice for capsule n into lw[buf] ----
    // 18 KB = 18 wave-transfers of 1 KB (64 lanes x 16 B); chunk c = (k*3+l),
    // global src = wt + c*16384 + n*512 (+half*256), contiguous 512 floats.
    auto stage = [&](int n, int buf) {
        for (int t = wv; t < 18; t += 4) {
            const int c = t >> 1, half = t & 1;
            const float* src = wt + c * 16384 + n * 512 + half * 256 + wlane * 4;
            float* dst = &lw[buf][c * 512 + half * 256];
            __builtin_amdgcn_global_load_lds((const ASG void*)src, (ASL void*)dst,
                                             16, 0, 0);
        }
    };

    stage(0, 0);

    // ncv[b, m=lane, h, wo, 0..15]
    const float* ncv_p = ncv + ((((size_t)b * 32 + lane) * HOUT + h) * WOUT + wo) * 16;
    float cv[16];
#pragma unroll
    for (int j = 0; j < 16; j += 4) {
        float4 t = *(const float4*)(ncv_p + j);
        cv[j] = t.x; cv[j + 1] = t.y; cv[j + 2] = t.z; cv[j + 3] = t.w;
    }

    float acc[16];
#pragma unroll
    for (int j = 0; j < 16; ++j) acc[j] = 0.0f;

    const int h0 = h * 2, w0 = wo * 2;
    // av tile offsets for kl = 0..8  ((k*32+l)*16)
    const int off[9] = {0, 16, 32, 512, 528, 544, 1024, 1040, 1056};

    __syncthreads();   // drain stage(0)

    for (int n = 0; n < 32; ++n) {
        if (n + 1 < 32) stage(n + 1, (n + 1) & 1);   // overlap with compute

        const float* wbuf = lw[n & 1];
        const float* ipn  = input + ((((size_t)b * 32 + n) * 32 + h0) * 32 + w0) * 16;

        float avb[2][16];
#pragma unroll
        for (int j = 0; j < 16; j += 4) {
            float4 t = *(const float4*)(ipn + j);
            avb[0][j] = t.x; avb[0][j+1] = t.y; avb[0][j+2] = t.z; avb[0][j+3] = t.w;
        }

#pragma unroll
        for (int kl = 0; kl < 9; ++kl) {
            const int cur = kl & 1;
            if (kl < 8) {                 // prefetch next av tile
                const float* ip = ipn + off[kl + 1];
#pragma unroll
                for (int j = 0; j < 16; j += 4) {
                    float4 t = *(const float4*)(ip + j);
                    avb[cur ^ 1][j]   = t.x; avb[cur ^ 1][j+1] = t.y;
                    avb[cur ^ 1][j+2] = t.z; avb[cur ^ 1][j+3] = t.w;
                }
            }
            const float* av = avb[cur];
            const float* wp = wbuf + kl * 512 + lane;

            // u[a,d] = sum_x av[a,x] * w[x,d,m]   (w from LDS, lane-coalesced)
            float u[16];
#pragma unroll
            for (int j = 0; j < 16; ++j) u[j] = 0.0f;
#pragma unroll
            for (int x = 0; x < 4; ++x) {
#pragma unroll
                for (int d = 0; d < 4; ++d) {
                    float wxd = wp[(x * 4 + d) * 32];
#pragma unroll
                    for (int a = 0; a < 4; ++a)
                        u[a * 4 + d] = fmaf(av[a * 4 + x], wxd, u[a * 4 + d]);
                }
            }

            // logit = 0.25 * <u, cv>  (4 partial chains to shorten latency)
            float l0 = 0.f, l1 = 0.f, l2 = 0.f, l3 = 0.f;
#pragma unroll
            for (int j = 0; j < 4; ++j) {
                l0 = fmaf(u[j],      cv[j],      l0);
                l1 = fmaf(u[j + 4],  cv[j + 4],  l1);
                l2 = fmaf(u[j + 8],  cv[j + 8],  l2);
                l3 = fmaf(u[j + 12], cv[j + 12], l3);
            }
            float logit = ((l0 + l1) + (l2 + l3)) * 0.25f;

            // softmax over m (32 lanes) -- no max-subtract: |logit| << 80,
            // fp32 exp cannot overflow; well inside the 7.2e-2 threshold.
            float e = __expf(logit);
            float s = e;
#pragma unroll
            for (int o = 16; o > 0; o >>= 1)
                s += __shfl_xor(s, o, 32);
            float p = e * __builtin_amdgcn_rcpf(s);

#pragma unroll
            for (int j = 0; j < 16; ++j) acc[j] = fmaf(p, u[j], acc[j]);
        }

        if (n < 31) __syncthreads();   // drain stage(n+1), protect lw reuse
    }

    // LayerNorm over the 16 register-resident elements (per lane = per m)
    float mu = 0.0f;
#pragma unroll
    for (int j = 0; j < 16; ++j) mu += acc[j];
    mu *= 0.0625f;
    float var = 0.0f;
#pragma unroll
    for (int j = 0; j < 16; ++j) { float d = acc[j] - mu; var = fmaf(d, d, var); }
    var *= 0.0625f;
    float rstd = __builtin_amdgcn_rsqf(var + 1e-5f);

    float* op = out + ((((size_t)b * 32 + lane) * HOUT + h) * WOUT + wo) * 16;
#pragma unroll
    for (int j = 0; j < 16; j += 4) {
        float4 g  = *(const float4*)(gamma + j);
        float4 be = *(const float4*)(beta + j);
        float4 r;
        r.x = (acc[j + 0] - mu) * rstd * g.x + be.x;
        r.y = (acc[j + 1] - mu) * rstd * g.y + be.y;
        r.z = (acc[j + 2] - mu) * rstd * g.z + be.z;
        r.w = (acc[j + 3] - mu) * rstd * g.w + be.w;
        *(float4*)(op + j) = r;
    }
}

extern "C" void kernel_launch(void* const* d_in, const int* in_sizes, int n_in,
                              void* d_out, int out_size, void* d_ws, size_t ws_size,
                              hipStream_t stream) {
    const float* input = (const float*)d_in[0];
    const float* ncv   = (const float*)d_in[1];
    const float* wt    = (const float*)d_in[2];
    const float* gamma = (const float*)d_in[3];
    const float* beta  = (const float*)d_in[4];
    float* out = (float*)d_out;

    caps_fused<<<dim3(900), dim3(256), 0, stream>>>(input, ncv, wt, gamma, beta, out);
}

// Round 3
// 395.277 us; speedup vs baseline: 4.1793x; 4.1793x over previous
//
#include <hip/hip_runtime.h>

#define HOUT 15
#define WOUT 15
// input  (32, 32, 32, 32, 16)  fp32
// ncv    (32, 32, 15, 15, 16)  fp32
// w      (3, 3, 32, 4, 4, 32)  fp32  -> slice per n: 9 chunks of 512 floats
// out    (32, 32, 15, 15, 16)  fp32

#define ASG __attribute__((address_space(1)))
#define ASL __attribute__((address_space(3)))

// One 32-lane group per output position (b,h,w); lane = m. 8 groups / block.
// Block loops n=0..31; w[:,:,n,:,:,:] staged in LDS (double-buffered, async).
// launch_bounds(256,2): VGPR cap 256 -- round 2 showed (256,4) forces 64 VGPRs
// and spills ~6 GB of scratch through HBM. LDS (36 KB) still permits 4 blk/CU.
__global__ __launch_bounds__(256, 2) void caps_fused(
    const float* __restrict__ input,
    const float* __restrict__ ncv,
    const float* __restrict__ wt,
    const float* __restrict__ gamma,
    const float* __restrict__ beta,
    float* __restrict__ out)
{
    __shared__ float lw[2][4608];   // 2 x 18KB

    const int tid   = threadIdx.x;
    const int grp   = tid >> 5;     // 0..7
    const int lane  = tid & 31;     // m
    const int wv    = tid >> 6;     // wave 0..3
    const int wlane = tid & 63;

    const int pos = blockIdx.x * 8 + grp;
    const int b   = pos / (HOUT * WOUT);
    const int hw  = pos % (HOUT * WOUT);
    const int h   = hw / WOUT;
    const int wo  = hw % WOUT;

    // ---- async stage of w slice for capsule n into lw[buf] ----
    // 18 KB = 18 wave-transfers of 1 KB (64 lanes x 16 B); chunk c = (k*3+l),
    // global src = wt + c*16384 + n*512 (+half*256), contiguous 512 floats.
    auto stage = [&](int n, int buf) {
        for (int t = wv; t < 18; t += 4) {
            const int c = t >> 1, half = t & 1;
            const float* src = wt + c * 16384 + n * 512 + half * 256 + wlane * 4;
            float* dst = &lw[buf][c * 512 + half * 256];
            __builtin_amdgcn_global_load_lds((const ASG void*)src, (ASL void*)dst,
                                             16, 0, 0);
        }
    };

    stage(0, 0);

    // ncv[b, m=lane, h, wo, 0..15]
    const float* ncv_p = ncv + ((((size_t)b * 32 + lane) * HOUT + h) * WOUT + wo) * 16;
    float cv[16];
#pragma unroll
    for (int j = 0; j < 16; j += 4) {
        float4 t = *(const float4*)(ncv_p + j);
        cv[j] = t.x; cv[j + 1] = t.y; cv[j + 2] = t.z; cv[j + 3] = t.w;
    }

    float acc[16];
#pragma unroll
    for (int j = 0; j < 16; ++j) acc[j] = 0.0f;

    const int h0 = h * 2, w0 = wo * 2;

    __syncthreads();   // drain stage(0)

    for (int n = 0; n < 32; ++n) {
        if (n + 1 < 32) stage(n + 1, (n + 1) & 1);   // overlap with compute

        const float* wbuf = lw[n & 1];
        const float* ipn  = input + ((((size_t)b * 32 + n) * 32 + h0) * 32 + w0) * 16;

#pragma unroll
        for (int k = 0; k < 3; ++k) {
#pragma unroll
            for (int l = 0; l < 3; ++l) {
                const int kl = k * 3 + l;
                // inp[b, n, 2h+k, 2w+l, 0..15] -- same addr for all 32 lanes
                // of the group (broadcast; coalesces to one line fetch).
                const float* ip = ipn + (k * 32 + l) * 16;
                float av[16];
#pragma unroll
                for (int j = 0; j < 16; j += 4) {
                    float4 t = *(const float4*)(ip + j);
                    av[j] = t.x; av[j + 1] = t.y; av[j + 2] = t.z; av[j + 3] = t.w;
                }

                const float* wp = wbuf + kl * 512 + lane;

                // u[a,d] = sum_x av[a,x] * w[x,d,m]   (w from LDS, lane-coalesced)
                float u[16];
#pragma unroll
                for (int j = 0; j < 16; ++j) u[j] = 0.0f;
#pragma unroll
                for (int x = 0; x < 4; ++x) {
#pragma unroll
                    for (int d = 0; d < 4; ++d) {
                        float wxd = wp[(x * 4 + d) * 32];
#pragma unroll
                        for (int a = 0; a < 4; ++a)
                            u[a * 4 + d] = fmaf(av[a * 4 + x], wxd, u[a * 4 + d]);
                    }
                }

                // logit = 0.25 * <u, cv>  (4 partial chains to shorten latency)
                float l0 = 0.f, l1 = 0.f, l2 = 0.f, l3 = 0.f;
#pragma unroll
                for (int j = 0; j < 4; ++j) {
                    l0 = fmaf(u[j],      cv[j],      l0);
                    l1 = fmaf(u[j + 4],  cv[j + 4],  l1);
                    l2 = fmaf(u[j + 8],  cv[j + 8],  l2);
                    l3 = fmaf(u[j + 12], cv[j + 12], l3);
                }
                float logit = ((l0 + l1) + (l2 + l3)) * 0.25f;

                // softmax over m (32 lanes) -- no max-subtract: |logit| << 80,
                // fp32 exp cannot overflow; well inside the 7.2e-2 threshold.
                float e = __expf(logit);
                float s = e;
#pragma unroll
                for (int o = 16; o > 0; o >>= 1)
                    s += __shfl_xor(s, o, 32);
                float p = e * __builtin_amdgcn_rcpf(s);

#pragma unroll
                for (int j = 0; j < 16; ++j) acc[j] = fmaf(p, u[j], acc[j]);
            }
        }

        if (n < 31) __syncthreads();   // drain stage(n+1), protect lw reuse
    }

    // LayerNorm over the 16 register-resident elements (per lane = per m)
    float mu = 0.0f;
#pragma unroll
    for (int j = 0; j < 16; ++j) mu += acc[j];
    mu *= 0.0625f;
    float var = 0.0f;
#pragma unroll
    for (int j = 0; j < 16; ++j) { float d = acc[j] - mu; var = fmaf(d, d, var); }
    var *= 0.0625f;
    float rstd = __builtin_amdgcn_rsqf(var + 1e-5f);

    float* op = out + ((((size_t)b * 32 + lane) * HOUT + h) * WOUT + wo) * 16;
#pragma unroll
    for (int j = 0; j < 16; j += 4) {
        float4 g  = *(const float4*)(gamma + j);
        float4 be = *(const float4*)(beta + j);
        float4 r;
        r.x = (acc[j + 0] - mu) * rstd * g.x + be.x;
        r.y = (acc[j + 1] - mu) * rstd * g.y + be.y;
        r.z = (acc[j + 2] - mu) * rstd * g.z + be.z;
        r.w = (acc[j + 3] - mu) * rstd * g.w + be.w;
        *(float4*)(op + j) = r;
    }
}

extern "C" void kernel_launch(void* const* d_in, const int* in_sizes, int n_in,
                              void* d_out, int out_size, void* d_ws, size_t ws_size,
                              hipStream_t stream) {
    const float* input = (const float*)d_in[0];
    const float* ncv   = (const float*)d_in[1];
    const float* wt    = (const float*)d_in[2];
    const float* gamma = (const float*)d_in[3];
    const float* beta  = (const float*)d_in[4];
    float* out = (float*)d_out;

    caps_fused<<<dim3(900), dim3(256), 0, stream>>>(input, ncv, wt, gamma, beta, out);
}

// Round 4
// 377.540 us; speedup vs baseline: 4.3756x; 1.0470x over previous
//
#include <hip/hip_runtime.h>

#define HOUT 15
#define WOUT 15
// input  (32, 32, 32, 32, 16)  fp32
// ncv    (32, 32, 15, 15, 16)  fp32
// w      (3, 3, 32, 4, 4, 32)  fp32
// out    (32, 32, 15, 15, 16)  fp32 = 3,686,400 floats

#define ASG __attribute__((address_space(1)))
#define ASL __attribute__((address_space(3)))

typedef float v2 __attribute__((ext_vector_type(2)));

// ---------------- pass 1: partial accumulation over half the n range -------
// One 32-lane group per output position (b,h,w); lane = m. 8 groups / block.
// blockIdx.y = n-split (0: n=0..15 -> d_out as partial, 1: n=16..31 -> d_ws).
// w[:,:,n,:,:,:] staged in LDS, double-buffered via async global_load_lds.
__global__ __launch_bounds__(256, 2) void caps_part(
    const float* __restrict__ input,
    const float* __restrict__ ncv,
    const float* __restrict__ wt,
    float* __restrict__ part0,
    float* __restrict__ part1)
{
    __shared__ float lw[2][4608];   // 2 x 18KB

    const int tid   = threadIdx.x;
    const int grp   = tid >> 5;     // 0..7
    const int lane  = tid & 31;     // m
    const int wv    = tid >> 6;     // wave 0..3
    const int wlane = tid & 63;

    const int pos = blockIdx.x * 8 + grp;
    const int b   = pos / (HOUT * WOUT);
    const int hw  = pos % (HOUT * WOUT);
    const int h   = hw / WOUT;
    const int wo  = hw % WOUT;

    const int s  = blockIdx.y;      // n-split
    const int n0 = s * 16;

    // async stage of w slice for capsule n: 18 KB = 18 x (64 lanes x 16 B)
    auto stage = [&](int n, int buf) {
        for (int t = wv; t < 18; t += 4) {
            const int c = t >> 1, half = t & 1;
            const float* src = wt + c * 16384 + n * 512 + half * 256 + wlane * 4;
            float* dst = &lw[buf][c * 512 + half * 256];
            __builtin_amdgcn_global_load_lds((const ASG void*)src, (ASL void*)dst,
                                             16, 0, 0);
        }
    };

    stage(n0, 0);

    // ncv[b, m=lane, h, wo, 0..15] packed as 8 x float2
    const float* ncv_p = ncv + ((((size_t)b * 32 + lane) * HOUT + h) * WOUT + wo) * 16;
    v2 cv2[8];
#pragma unroll
    for (int j = 0; j < 8; ++j) cv2[j] = *(const v2*)(ncv_p + j * 2);

    v2 acc2[8];
#pragma unroll
    for (int j = 0; j < 8; ++j) acc2[j] = (v2){0.0f, 0.0f};

    const int h0 = h * 2, w0 = wo * 2;

    __syncthreads();   // drain stage(n0)

    for (int i = 0; i < 16; ++i) {
        const int n = n0 + i;
        if (i + 1 < 16) stage(n + 1, (i + 1) & 1);   // overlap with compute

        const float* wbuf = lw[i & 1];
        const float* ipn  = input + ((((size_t)b * 32 + n) * 32 + h0) * 32 + w0) * 16;

#pragma unroll
        for (int k = 0; k < 3; ++k) {
#pragma unroll
            for (int l = 0; l < 3; ++l) {
                const int kl = k * 3 + l;
                const float* ip = ipn + (k * 32 + l) * 16;
                float av[16];
#pragma unroll
                for (int j = 0; j < 16; j += 4) {
                    float4 t = *(const float4*)(ip + j);
                    av[j] = t.x; av[j + 1] = t.y; av[j + 2] = t.z; av[j + 3] = t.w;
                }

                const float* wp = wbuf + kl * 512 + lane;

                // u[a,d] = sum_x av[a,x]*w[x,d,m]; packed d-pairs -> v_pk_fma_f32
                v2 u2[8];
#pragma unroll
                for (int j = 0; j < 8; ++j) u2[j] = (v2){0.0f, 0.0f};
#pragma unroll
                for (int x = 0; x < 4; ++x) {
                    float wd0 = wp[(x * 4 + 0) * 32];
                    float wd1 = wp[(x * 4 + 1) * 32];
                    float wd2 = wp[(x * 4 + 2) * 32];
                    float wd3 = wp[(x * 4 + 3) * 32];
                    v2 wlo = {wd0, wd1};
                    v2 whi = {wd2, wd3};
#pragma unroll
                    for (int a = 0; a < 4; ++a) {
                        v2 sp = {av[a * 4 + x], av[a * 4 + x]};
                        u2[a * 2 + 0] = __builtin_elementwise_fma(sp, wlo, u2[a * 2 + 0]);
                        u2[a * 2 + 1] = __builtin_elementwise_fma(sp, whi, u2[a * 2 + 1]);
                    }
                }

                // logit = 0.25 * <u, cv>
                v2 d0 = {0.f, 0.f}, d1 = {0.f, 0.f};
#pragma unroll
                for (int j = 0; j < 4; ++j) {
                    d0 = __builtin_elementwise_fma(u2[j],     cv2[j],     d0);
                    d1 = __builtin_elementwise_fma(u2[j + 4], cv2[j + 4], d1);
                }
                v2 dd = d0 + d1;
                float logit = (dd.x + dd.y) * 0.25f;

                // softmax over m (32 lanes); no max-subtract (|logit| << 80)
                float e = __expf(logit);
                float sum = e;
#pragma unroll
                for (int o = 16; o > 0; o >>= 1)
                    sum += __shfl_xor(sum, o, 32);
                float p = e * __builtin_amdgcn_rcpf(sum);
                v2 p2 = {p, p};

#pragma unroll
                for (int j = 0; j < 8; ++j)
                    acc2[j] = __builtin_elementwise_fma(p2, u2[j], acc2[j]);
            }
        }

        if (i < 15) __syncthreads();   // drain next stage, protect lw reuse
    }

    // store partial in out-layout: [b][m][h][w][16]
    float* op = (s == 0 ? part0 : part1)
              + ((((size_t)b * 32 + lane) * HOUT + h) * WOUT + wo) * 16;
#pragma unroll
    for (int j = 0; j < 4; ++j) {
        float4 r;
        r.x = acc2[2 * j].x;     r.y = acc2[2 * j].y;
        r.z = acc2[2 * j + 1].x; r.w = acc2[2 * j + 1].y;
        *(float4*)(op + j * 4) = r;
    }
}

// ---------------- pass 2: combine partials + LayerNorm ---------------------
// 230400 (pos,m) rows of 16; fully coalesced. In-place on part0 (= d_out).
__global__ __launch_bounds__(256) void caps_ln(
    const float* __restrict__ part1,
    const float* __restrict__ gamma,
    const float* __restrict__ beta,
    float* __restrict__ out)
{
    const size_t t = (size_t)blockIdx.x * 256 + threadIdx.x;  // 0..230399
    const float* p0 = out   + t * 16;
    const float* p1 = part1 + t * 16;

    float a[16];
#pragma unroll
    for (int j = 0; j < 16; j += 4) {
        float4 x = *(const float4*)(p0 + j);
        float4 y = *(const float4*)(p1 + j);
        a[j] = x.x + y.x; a[j+1] = x.y + y.y; a[j+2] = x.z + y.z; a[j+3] = x.w + y.w;
    }

    float mu = 0.0f;
#pragma unroll
    for (int j = 0; j < 16; ++j) mu += a[j];
    mu *= 0.0625f;
    float var = 0.0f;
#pragma unroll
    for (int j = 0; j < 16; ++j) { float d = a[j] - mu; var = fmaf(d, d, var); }
    var *= 0.0625f;
    float rstd = __builtin_amdgcn_rsqf(var + 1e-5f);

    float* op = out + t * 16;
#pragma unroll
    for (int j = 0; j < 16; j += 4) {
        float4 g  = *(const float4*)(gamma + j);
        float4 be = *(const float4*)(beta + j);
        float4 r;
        r.x = (a[j + 0] - mu) * rstd * g.x + be.x;
        r.y = (a[j + 1] - mu) * rstd * g.y + be.y;
        r.z = (a[j + 2] - mu) * rstd * g.z + be.z;
        r.w = (a[j + 3] - mu) * rstd * g.w + be.w;
        *(float4*)(op + j) = r;
    }
}

extern "C" void kernel_launch(void* const* d_in, const int* in_sizes, int n_in,
                              void* d_out, int out_size, void* d_ws, size_t ws_size,
                              hipStream_t stream) {
    const float* input = (const float*)d_in[0];
    const float* ncv   = (const float*)d_in[1];
    const float* wt    = (const float*)d_in[2];
    const float* gamma = (const float*)d_in[3];
    const float* beta  = (const float*)d_in[4];
    float* out  = (float*)d_out;
    float* ws   = (float*)d_ws;    // 14.7 MB partial for split 1

    caps_part<<<dim3(900, 2), dim3(256), 0, stream>>>(input, ncv, wt, out, ws);
    caps_ln<<<dim3(900), dim3(256), 0, stream>>>(ws, gamma, beta, out);
}